// Round 8
// baseline (311.142 us; speedup 1.0000x reference)
//
#include <hip/hip_runtime.h>
#include <cstdint>

#define BB 2
#define SS 2048
#define DD 2048
#define HH 16
#define HDIM 128
#define MM (BB * SS)  // 4096

typedef __attribute__((ext_vector_type(8))) short bf16x8;
typedef __attribute__((ext_vector_type(4))) short bf16x4;
typedef __attribute__((ext_vector_type(4))) float f32x4;
typedef __attribute__((ext_vector_type(16))) float f32x16;

__device__ inline short f2bf(float f) {
  union { float f; unsigned u; } v; v.f = f;
  unsigned r = v.u + 0x7FFFu + ((v.u >> 16) & 1u);
  return (short)(r >> 16);
}
__device__ inline float bf2f(short s) {
  union { float f; unsigned u; } v;
  v.u = ((unsigned)(unsigned short)s) << 16;
  return v.f;
}
__device__ inline float asf(int u) { union { int i; float f; } v; v.i = u; return v.f; }
__device__ inline int asi(float f) { union { float f; int i; } v; v.f = f; return v.i; }

__device__ inline unsigned cvtpk_bf16(float lo, float hi) {
  unsigned r;
  asm("v_cvt_pk_bf16_f32 %0, %1, %2" : "=v"(r) : "v"(lo), "v"(hi));
  return r;
}

__device__ inline void gll16(const void* g, void* l) {
  __builtin_amdgcn_global_load_lds(
      (const __attribute__((address_space(1))) void*)g,
      (__attribute__((address_space(3))) void*)l, 16, 0, 0);
}

// ---------------- cast fp32 -> bf16 ----------------
__global__ __launch_bounds__(256) void cast_bf16_kernel(
    const float* __restrict__ x, short* __restrict__ y, int n4) {
  int i = blockIdx.x * 256 + threadIdx.x;
  if (i >= n4) return;
  float4 v = reinterpret_cast<const float4*>(x)[i];
  bf16x4 o;
  o[0] = f2bf(v.x); o[1] = f2bf(v.y); o[2] = f2bf(v.z); o[3] = f2bf(v.w);
  reinterpret_cast<bf16x4*>(y)[i] = o;
}

// ---------------- all 4 weight transposes in ONE launch (z = 0..3) ----------------
__global__ __launch_bounds__(256) void transpose4_kernel(
    const float* __restrict__ Wq, const float* __restrict__ Wk,
    const float* __restrict__ Wv, const float* __restrict__ Wo,
    short* __restrict__ WqkvT, short* __restrict__ WoT) {
  __shared__ short tile[64][65];
  int z = blockIdx.z;
  const float* W = (z == 0) ? Wq : (z == 1) ? Wk : (z == 2) ? Wv : Wo;
  short* Wt = (z < 3) ? (WqkvT + (size_t)z * DD * DD) : WoT;
  int c = threadIdx.x & 63, r4 = threadIdx.x >> 6;
  int n0 = blockIdx.x << 6, k0 = blockIdx.y << 6;
#pragma unroll
  for (int p = 0; p < 16; ++p) {
    int r = (p << 2) + r4;
    tile[c][r] = f2bf(W[(size_t)(k0 + r) * DD + n0 + c]);
  }
  __syncthreads();
#pragma unroll
  for (int p = 0; p < 16; ++p) {
    int r = (p << 2) + r4;
    Wt[(size_t)(n0 + r) * DD + k0 + c] = tile[r][c];
  }
}

// ---------------- fused QKV GEMM (r4 structure + XCD-chunked grid) ----------------
// C(4096,6144) = xb * WqkvT^T. 128x128 tile, BK=64, 4 waves, 34KB LDS
// (4 blocks/CU co-resident — the TLP that hides the barrier drains).
// Grid 1536 1-D: xcd = id&7 owns a 6-wide tn strip (B panel 3.1MB, L2-resident).
// Epilogues: mat 0/1 RoPE (Q pre-scaled log2e/sqrt(128)); mat 2 V-transpose
// via LDS -> Vt (B*H,128,S).
__global__ __launch_bounds__(256) void qkv_gemm_kernel(
    const short* __restrict__ A, const short* __restrict__ Bt,
    short* __restrict__ Qb, short* __restrict__ Kb, short* __restrict__ Vt,
    const float* __restrict__ fc, const float* __restrict__ fs) {
  __shared__ short smem[128 * 136];  // As(8192)+Bs(8192); epilogue reuses as Tt
  short* As = smem;
  short* Bs = smem + 8192;
  const int tid = threadIdx.x;
  const int lane = tid & 63, w = tid >> 6;
  const int cl = lane & 15, gq = lane >> 4;
  const int wm = w >> 1, wn = w & 1;
  const int xcd = blockIdx.x & 7, local = blockIdx.x >> 3;  // local 0..191
  const int tn = xcd * 6 + local % 6, tm = local / 6;
  const int m0 = tm << 7, n0 = tn << 7;
  const int mat = n0 >> 11;  // 0=Q 1=K 2=V
  f32x4 acc[4][4];
#pragma unroll
  for (int i = 0; i < 4; ++i)
#pragma unroll
    for (int j = 0; j < 4; ++j) {
      f32x4 z = {0.f, 0.f, 0.f, 0.f};
      acc[i][j] = z;
    }
  const int lrow = lane >> 3;
  const int lseg = (lane & 7) ^ lrow;

  for (int k0 = 0; k0 < DD; k0 += 64) {
#pragma unroll
    for (int i = 0; i < 4; ++i) {
      int r0 = ((w << 2) + i) << 3;
      gll16(&A[(size_t)(m0 + r0 + lrow) * DD + k0 + (lseg << 3)], &As[r0 << 6]);
      gll16(&Bt[(size_t)(n0 + r0 + lrow) * DD + k0 + (lseg << 3)], &Bs[r0 << 6]);
    }
    __syncthreads();
#pragma unroll
    for (int ks = 0; ks < 2; ++ks) {
      bf16x8 af[4], bfr[4];
#pragma unroll
      for (int f = 0; f < 4; ++f) {
        int ra = (wm << 6) + (f << 4) + cl;
        af[f] = *reinterpret_cast<const bf16x8*>(
            &As[((ra << 6) + (ks << 5) + (gq << 3)) ^ ((ra & 7) << 3)]);
        int rb = (wn << 6) + (f << 4) + cl;
        bfr[f] = *reinterpret_cast<const bf16x8*>(
            &Bs[((rb << 6) + (ks << 5) + (gq << 3)) ^ ((rb & 7) << 3)]);
      }
#pragma unroll
      for (int fm = 0; fm < 4; ++fm)
#pragma unroll
        for (int fn = 0; fn < 4; ++fn)
          acc[fm][fn] = __builtin_amdgcn_mfma_f32_16x16x32_bf16(
              af[fm], bfr[fn], acc[fm][fn], 0, 0, 0);
    }
    __syncthreads();
  }

  if (mat < 2) {
    const float qs = (mat == 0) ? 0.127517448f : 1.0f;  // log2e/sqrt(128)
    short* Dst = (mat == 0) ? Qb : Kb;
#pragma unroll
    for (int fm = 0; fm < 4; ++fm)
#pragma unroll
      for (int r = 0; r < 4; ++r) {
        int mrow = m0 + (wm << 6) + (fm << 4) + (gq << 2) + r;
        int s = mrow & (SS - 1);
#pragma unroll
        for (int fn = 0; fn < 4; ++fn) {
          int c = (wn << 6) + (fn << 4) + cl;  // head-local col 0..127
          int i = c >> 1;
          float cv = fc[s * 64 + i], sv = fs[s * 64 + i];
          float v = acc[fm][fn][r];
          float vp = __shfl_xor(v, 1, 64);
          float o = (c & 1) ? (v * cv + vp * sv) : (v * cv - vp * sv);
          Dst[(size_t)mrow * DD + ((n0 + c) & (DD - 1))] = f2bf(o * qs);
        }
      }
  } else {
    // V epilogue: transpose via LDS, write Vt (B*H,128,S)
    short* Tt = smem;  // [c][r] stride 136 shorts
#pragma unroll
    for (int fm = 0; fm < 4; ++fm)
#pragma unroll
      for (int fn = 0; fn < 4; ++fn) {
        int c = (wn << 6) + (fn << 4) + cl;
        int rb = (wm << 6) + (fm << 4) + (gq << 2);
        bf16x4 v4;
#pragma unroll
        for (int rr = 0; rr < 4; ++rr) v4[rr] = f2bf(acc[fm][fn][rr]);
        *reinterpret_cast<bf16x4*>(&Tt[c * 136 + rb]) = v4;
      }
    __syncthreads();
    int d = tid >> 1, half = tid & 1;
    int bq = m0 >> 11, s0loc = m0 & (SS - 1);
    int hv = tn - 32;  // head 0..15
    size_t vb = (((size_t)(bq * 16 + hv) * HDIM + d) * SS) + s0loc + half * 64;
#pragma unroll
    for (int j = 0; j < 8; ++j) {
      bf16x8 v = *reinterpret_cast<const bf16x8*>(&Tt[d * 136 + half * 64 + j * 8]);
      *reinterpret_cast<bf16x8*>(&Vt[vb + j * 8]) = v;
    }
  }
}

// ---------------- Wo GEMM (r4 structure + XCD-chunked grid), fp32 out ----------------
__global__ __launch_bounds__(256) void gemm_kernel(
    const short* __restrict__ A, const short* __restrict__ Bt, float* __restrict__ C,
    int Mdim, int Ndim, int Kdim) {
  __shared__ short As[128 * 64];
  __shared__ short Bs[128 * 64];
  int tid = threadIdx.x;
  int lane = tid & 63, w = tid >> 6;
  int cl = lane & 15, gq = lane >> 4;
  int wm = w >> 1, wn = w & 1;
  const int xcd = blockIdx.x & 7, local = blockIdx.x >> 3;  // local 0..63
  const int tn = xcd * 2 + (local & 1), tm = local >> 1;
  int m0 = tm << 7, n0 = tn << 7;
  f32x4 acc[4][4];
#pragma unroll
  for (int i = 0; i < 4; ++i)
#pragma unroll
    for (int j = 0; j < 4; ++j) {
      f32x4 z = {0.f, 0.f, 0.f, 0.f};
      acc[i][j] = z;
    }
  int lrow = lane >> 3;
  int lseg = (lane & 7) ^ lrow;

  for (int k0 = 0; k0 < Kdim; k0 += 64) {
#pragma unroll
    for (int i = 0; i < 4; ++i) {
      int r0 = ((w << 2) + i) << 3;
      gll16(&A[(size_t)(m0 + r0 + lrow) * Kdim + k0 + (lseg << 3)], &As[r0 << 6]);
      gll16(&Bt[(size_t)(n0 + r0 + lrow) * Kdim + k0 + (lseg << 3)], &Bs[r0 << 6]);
    }
    __syncthreads();
#pragma unroll
    for (int ks = 0; ks < 2; ++ks) {
      bf16x8 af[4], bfr[4];
#pragma unroll
      for (int f = 0; f < 4; ++f) {
        int ra = (wm << 6) + (f << 4) + cl;
        af[f] = *reinterpret_cast<const bf16x8*>(
            &As[((ra << 6) + (ks << 5) + (gq << 3)) ^ ((ra & 7) << 3)]);
        int rb = (wn << 6) + (f << 4) + cl;
        bfr[f] = *reinterpret_cast<const bf16x8*>(
            &Bs[((rb << 6) + (ks << 5) + (gq << 3)) ^ ((rb & 7) << 3)]);
      }
#pragma unroll
      for (int fm = 0; fm < 4; ++fm)
#pragma unroll
        for (int fn = 0; fn < 4; ++fn)
          acc[fm][fn] = __builtin_amdgcn_mfma_f32_16x16x32_bf16(
              af[fm], bfr[fn], acc[fm][fn], 0, 0, 0);
    }
    __syncthreads();
  }
#pragma unroll
  for (int fm = 0; fm < 4; ++fm)
#pragma unroll
    for (int r = 0; r < 4; ++r) {
      int mrow = m0 + (wm << 6) + (fm << 4) + (gq << 2) + r;
#pragma unroll
      for (int fn = 0; fn < 4; ++fn) {
        int ncol = n0 + (wn << 6) + (fn << 4) + cl;
        C[(size_t)mrow * Ndim + ncol] = acc[fm][fn][r];
      }
    }
}

// ---------------- flash attention: 3 blocks/CU, single-buffered V ----------------
// LDS 48KB (K dbuf 32KB + V 16KB) -> 3 blocks/CU; 512 blocks all co-resident.
// Per tile: issue V[t]+K[t+1]; vmcnt(8) waits K[t] (K[t+1],V[t] fly); barrier;
// QK+softmax; vmcnt(4) waits V[t] (K[t+1] flies); barrier; PV; barrier (Vl
// reuse guard). Counted vmcnts exact: Q-frag loads drained pre-loop.
__global__ __launch_bounds__(256, 3) void attn_kernel(
    const short* __restrict__ Q, const short* __restrict__ K,
    const short* __restrict__ Vt, short* __restrict__ O) {
  __shared__ short Kl[2][64 * 128];  // 32KB
  __shared__ short Vl[128 * 64];     // 16KB
  const int id = blockIdx.x;
  const int qi = 15 - (id >> 5);     // LPT: heavy blocks first
  const int bh = id & 31;
  const int b = bh >> 4, h = bh & 15;
  const int tid = threadIdx.x;
  const int lane = tid & 63, w = tid >> 6;
  const int l31 = lane & 31, hi = lane >> 5;
  const int qw = qi * 128 + w * 32;
  const int qg = qw + l31;

  const short* Kbase = K + (size_t)b * SS * DD + h * HDIM;
  const short* Vbase = Vt + (size_t)bh * HDIM * SS;
  int krow[4], kq[4], vd[4], vs[4];
#pragma unroll
  for (int i = 0; i < 4; ++i) {
    int c = w * 4 + i;
    krow[i] = c * 4 + (lane >> 4);
    kq[i] = (lane & 15) ^ (krow[i] & 7);
    vd[i] = c * 8 + (lane >> 3);
    vs[i] = (lane & 7) ^ (vd[i] & 7);
  }

  bf16x8 qf[8];
  const size_t qoff = ((size_t)b * SS + qg) * DD + h * HDIM;
#pragma unroll
  for (int s = 0; s < 8; ++s)
    qf[s] = *reinterpret_cast<const bf16x8*>(&Q[qoff + s * 16 + hi * 8]);
  // drain Q loads so hand-counted vmcnts below are exact
  asm volatile("s_waitcnt vmcnt(0)" ::: "memory");
  __builtin_amdgcn_sched_barrier(0);

  f32x16 ot[4];
#pragma unroll
  for (int dt = 0; dt < 4; ++dt)
#pragma unroll
    for (int r = 0; r < 16; ++r) ot[dt][r] = 0.f;
  float m_run = -INFINITY, l_run = 0.f;

  const int NT = 2 * qi + 2;

  // prologue: issue K[0] into Kl[0]
#pragma unroll
  for (int i = 0; i < 4; ++i)
    gll16(Kbase + (size_t)krow[i] * DD + kq[i] * 8, &Kl[0][(w * 4 + i) * 512]);

  for (int t = 0; t < NT; ++t) {
    const int cur = t & 1;
    const bool more = (t + 1 < NT);
    // issue V[t] (Vl free: post-PV barrier of t-1 passed)
#pragma unroll
    for (int i = 0; i < 4; ++i)
      gll16(Vbase + (size_t)vd[i] * SS + t * 64 + vs[i] * 8, &Vl[(w * 4 + i) * 512]);
    // issue K[t+1]
    if (more) {
#pragma unroll
      for (int i = 0; i < 4; ++i)
        gll16(Kbase + (size_t)((t + 1) * 64 + krow[i]) * DD + kq[i] * 8,
              &Kl[cur ^ 1][(w * 4 + i) * 512]);
      asm volatile("s_waitcnt vmcnt(8)" ::: "memory");  // K[t] landed
    } else {
      asm volatile("s_waitcnt vmcnt(4)" ::: "memory");  // K[t] landed
    }
    __builtin_amdgcn_sched_barrier(0);
    __builtin_amdgcn_s_barrier();
    __builtin_amdgcn_sched_barrier(0);

    const bool work = (t * 64 <= qw + 31);
    f32x16 st0, st1;
    bf16x8 pf[4];
    if (work) {
      const short* Kc = Kl[cur];
#pragma unroll
      for (int r = 0; r < 16; ++r) { st0[r] = 0.f; st1[r] = 0.f; }
      __builtin_amdgcn_s_setprio(1);
#pragma unroll
      for (int s = 0; s < 8; ++s) {
        const int cs = (s * 2 + hi);
        bf16x8 kf0 = *reinterpret_cast<const bf16x8*>(
            &Kc[l31 * 128 + ((cs ^ (l31 & 7)) << 3)]);
        st0 = __builtin_amdgcn_mfma_f32_32x32x16_bf16(kf0, qf[s], st0, 0, 0, 0);
        bf16x8 kf1 = *reinterpret_cast<const bf16x8*>(
            &Kc[(32 + l31) * 128 + ((cs ^ (l31 & 7)) << 3)]);
        st1 = __builtin_amdgcn_mfma_f32_32x32x16_bf16(kf1, qf[s], st1, 0, 0, 0);
      }
      __builtin_amdgcn_s_setprio(0);
      if (t * 64 + 63 > qw) {
#pragma unroll
        for (int r = 0; r < 16; ++r) {
          int dl = (r & 3) + 8 * (r >> 2) + 4 * hi;
          if (t * 64 + dl > qg) st0[r] = -1e30f;
          if (t * 64 + 32 + dl > qg) st1[r] = -1e30f;
        }
      }
      // online softmax (base-2), tree reductions, defer-max
      float mx[16];
#pragma unroll
      for (int r = 0; r < 16; ++r) mx[r] = fmaxf(st0[r], st1[r]);
#pragma unroll
      for (int off = 8; off >= 1; off >>= 1)
#pragma unroll
        for (int r = 0; r < 8; ++r)
          if (r < off) mx[r] = fmaxf(mx[r], mx[r + off]);
      float pm = mx[0];
      {
        auto sw = __builtin_amdgcn_permlane32_swap(asi(pm), asi(pm), false, false);
        pm = fmaxf(asf(sw[0]), asf(sw[1]));
      }
      if (!__all(pm <= m_run + 11.5f)) {
        float mn = fmaxf(m_run, pm);
        float al = exp2f(m_run - mn);
        m_run = mn;
        l_run *= al;
#pragma unroll
        for (int dt = 0; dt < 4; ++dt)
#pragma unroll
          for (int r = 0; r < 16; ++r) ot[dt][r] *= al;
      }
#pragma unroll
      for (int r = 0; r < 16; ++r) st0[r] = exp2f(st0[r] - m_run);
#pragma unroll
      for (int r = 0; r < 16; ++r) st1[r] = exp2f(st1[r] - m_run);
      float sm[16];
#pragma unroll
      for (int r = 0; r < 16; ++r) sm[r] = st0[r] + st1[r];
#pragma unroll
      for (int off = 8; off >= 1; off >>= 1)
#pragma unroll
        for (int r = 0; r < 8; ++r)
          if (r < off) sm[r] += sm[r + off];
      float ps = sm[0];
      {
        auto sw = __builtin_amdgcn_permlane32_swap(asi(ps), asi(ps), false, false);
        ps = asf(sw[0]) + asf(sw[1]);
      }
      l_run += ps;

      // pack P -> bf16 B-frags (T12)
#pragma unroll
      for (int s = 0; s < 4; ++s) {
        float e0, e1, e2, e3, e4, e5, e6, e7;
        if (s < 2) {
          e0 = st0[8 * s + 0]; e1 = st0[8 * s + 1]; e2 = st0[8 * s + 2]; e3 = st0[8 * s + 3];
          e4 = st0[8 * s + 4]; e5 = st0[8 * s + 5]; e6 = st0[8 * s + 6]; e7 = st0[8 * s + 7];
        } else {
          e0 = st1[8 * (s - 2) + 0]; e1 = st1[8 * (s - 2) + 1]; e2 = st1[8 * (s - 2) + 2]; e3 = st1[8 * (s - 2) + 3];
          e4 = st1[8 * (s - 2) + 4]; e5 = st1[8 * (s - 2) + 5]; e6 = st1[8 * (s - 2) + 6]; e7 = st1[8 * (s - 2) + 7];
        }
        unsigned a0 = cvtpk_bf16(e0, e1);
        unsigned a1 = cvtpk_bf16(e2, e3);
        unsigned b0 = cvtpk_bf16(e4, e5);
        unsigned b1 = cvtpk_bf16(e6, e7);
        auto r0 = __builtin_amdgcn_permlane32_swap((int)a0, (int)b0, false, false);
        auto r1 = __builtin_amdgcn_permlane32_swap((int)a1, (int)b1, false, false);
        union { int u[4]; bf16x8 v; } pk;
        pk.u[0] = r0[0]; pk.u[1] = r1[0]; pk.u[2] = r0[1]; pk.u[3] = r1[1];
        pf[s] = pk.v;
      }
    }

    // V[t] landed for all waves (K[t+1] still flying)
    if (more)
      asm volatile("s_waitcnt vmcnt(4)" ::: "memory");
    else
      asm volatile("s_waitcnt vmcnt(0)" ::: "memory");
    __builtin_amdgcn_sched_barrier(0);
    __builtin_amdgcn_s_barrier();
    __builtin_amdgcn_sched_barrier(0);

    if (work) {
      __builtin_amdgcn_s_setprio(1);
#pragma unroll
      for (int dt = 0; dt < 4; ++dt) {
        const int vr = dt * 32 + l31;
#pragma unroll
        for (int s = 0; s < 4; ++s) {
          bf16x8 vf = *reinterpret_cast<const bf16x8*>(
              &Vl[vr * 64 + (((s * 2 + hi) ^ (vr & 7)) << 3)]);
          ot[dt] = __builtin_amdgcn_mfma_f32_32x32x16_bf16(vf, pf[s], ot[dt], 0, 0, 0);
        }
      }
      __builtin_amdgcn_s_setprio(0);
    }
    // guard Vl reuse by next iteration's V issue
    __builtin_amdgcn_sched_barrier(0);
    __builtin_amdgcn_s_barrier();
    __builtin_amdgcn_sched_barrier(0);
  }

  float inv = 1.0f / l_run;
  const size_t orow = ((size_t)b * SS + qg) * DD + h * HDIM;
#pragma unroll
  for (int dt = 0; dt < 4; ++dt)
#pragma unroll
    for (int g = 0; g < 4; ++g) {
      bf16x4 v;
#pragma unroll
      for (int k = 0; k < 4; ++k) v[k] = f2bf(ot[dt][4 * g + k] * inv);
      *reinterpret_cast<bf16x4*>(&O[orow + dt * 32 + 8 * g + 4 * hi]) = v;
    }
}

extern "C" void kernel_launch(void* const* d_in, const int* in_sizes, int n_in,
                              void* d_out, int out_size, void* d_ws, size_t ws_size,
                              hipStream_t stream) {
  const float* x = (const float*)d_in[0];
  const float* Wq = (const float*)d_in[1];
  const float* Wk = (const float*)d_in[2];
  const float* Wv = (const float*)d_in[3];
  const float* Wo = (const float*)d_in[4];
  const float* fc = (const float*)d_in[5];
  const float* fs = (const float*)d_in[6];
  float* out = (float*)d_out;
  char* ws = (char*)d_ws;

  short* xb     = (short*)(ws + 0);                      // 16MB; reused as attn_out
  short* WqkvT  = (short*)(ws + (size_t)16 * 1048576);   // 24MB
  short* WoT    = (short*)(ws + (size_t)40 * 1048576);   // 8MB
  short* Qb     = (short*)(ws + (size_t)48 * 1048576);   // 16MB
  short* Kb     = (short*)(ws + (size_t)64 * 1048576);   // 16MB
  short* VtB    = (short*)(ws + (size_t)80 * 1048576);   // 16MB (V transposed)

  cast_bf16_kernel<<<8192, 256, 0, stream>>>(x, xb, 2097152);
  transpose4_kernel<<<dim3(32, 32, 4), 256, 0, stream>>>(Wq, Wk, Wv, Wo, WqkvT, WoT);

  qkv_gemm_kernel<<<1536, 256, 0, stream>>>(xb, WqkvT, Qb, Kb, VtB, fc, fs);

  attn_kernel<<<512, 256, 0, stream>>>(Qb, Kb, VtB, xb);  // attn_out = xb

  gemm_kernel<<<512, 256, 0, stream>>>(xb, WoT, out, MM, DD, DD);
}

// Round 9
// 276.420 us; speedup vs baseline: 1.1256x; 1.1256x over previous
//
#include <hip/hip_runtime.h>
#include <cstdint>

#define BB 2
#define SS 2048
#define DD 2048
#define HH 16
#define HDIM 128
#define MM (BB * SS)  // 4096

typedef __attribute__((ext_vector_type(8))) short bf16x8;
typedef __attribute__((ext_vector_type(4))) short bf16x4;
typedef __attribute__((ext_vector_type(4))) float f32x4;
typedef __attribute__((ext_vector_type(16))) float f32x16;

__device__ inline short f2bf(float f) {
  union { float f; unsigned u; } v; v.f = f;
  unsigned r = v.u + 0x7FFFu + ((v.u >> 16) & 1u);
  return (short)(r >> 16);
}
__device__ inline float bf2f(short s) {
  union { float f; unsigned u; } v;
  v.u = ((unsigned)(unsigned short)s) << 16;
  return v.f;
}
__device__ inline float asf(int u) { union { int i; float f; } v; v.i = u; return v.f; }
__device__ inline int asi(float f) { union { float f; int i; } v; v.f = f; return v.i; }

__device__ inline unsigned cvtpk_bf16(float lo, float hi) {
  unsigned r;
  asm("v_cvt_pk_bf16_f32 %0, %1, %2" : "=v"(r) : "v"(lo), "v"(hi));
  return r;
}

__device__ inline void gll16(const void* g, void* l) {
  __builtin_amdgcn_global_load_lds(
      (const __attribute__((address_space(1))) void*)g,
      (__attribute__((address_space(3))) void*)l, 16, 0, 0);
}

// ---------------- cast fp32 -> bf16 ----------------
__global__ __launch_bounds__(256) void cast_bf16_kernel(
    const float* __restrict__ x, short* __restrict__ y, int n4) {
  int i = blockIdx.x * 256 + threadIdx.x;
  if (i >= n4) return;
  float4 v = reinterpret_cast<const float4*>(x)[i];
  bf16x4 o;
  o[0] = f2bf(v.x); o[1] = f2bf(v.y); o[2] = f2bf(v.z); o[3] = f2bf(v.w);
  reinterpret_cast<bf16x4*>(y)[i] = o;
}

// ---------------- all 4 weight transposes in ONE launch (z = 0..3) ----------------
__global__ __launch_bounds__(256) void transpose4_kernel(
    const float* __restrict__ Wq, const float* __restrict__ Wk,
    const float* __restrict__ Wv, const float* __restrict__ Wo,
    short* __restrict__ WqkvT, short* __restrict__ WoT) {
  __shared__ short tile[64][65];
  int z = blockIdx.z;
  const float* W = (z == 0) ? Wq : (z == 1) ? Wk : (z == 2) ? Wv : Wo;
  short* Wt = (z < 3) ? (WqkvT + (size_t)z * DD * DD) : WoT;
  int c = threadIdx.x & 63, r4 = threadIdx.x >> 6;
  int n0 = blockIdx.x << 6, k0 = blockIdx.y << 6;
#pragma unroll
  for (int p = 0; p < 16; ++p) {
    int r = (p << 2) + r4;
    tile[c][r] = f2bf(W[(size_t)(k0 + r) * DD + n0 + c]);
  }
  __syncthreads();
#pragma unroll
  for (int p = 0; p < 16; ++p) {
    int r = (p << 2) + r4;
    Wt[(size_t)(n0 + r) * DD + k0 + c] = tile[r][c];
  }
}

// ---------------- fused QKV GEMM: C(4096,6144) = xb * WqkvT^T ----------------
// 128x128 tile, BK=64, 4 waves, 34KB LDS (4 blocks/CU co-resident).
// Grid dim3(32,48): x = tm (FASTEST) -> concurrently-resident blocks span few
// tn columns -> live B footprint ~5MB (L2-resident), A (16MB) L3-resident.
// Epilogues: mat 0/1 RoPE (Q pre-scaled log2e/sqrt(128)); mat 2 V-transpose
// via LDS -> Vt (B*H,128,S).
__global__ __launch_bounds__(256) void qkv_gemm_kernel(
    const short* __restrict__ A, const short* __restrict__ Bt,
    short* __restrict__ Qb, short* __restrict__ Kb, short* __restrict__ Vt,
    const float* __restrict__ fc, const float* __restrict__ fs) {
  __shared__ short smem[128 * 136];  // As(8192)+Bs(8192); epilogue reuses as Tt
  short* As = smem;
  short* Bs = smem + 8192;
  const int tid = threadIdx.x;
  const int lane = tid & 63, w = tid >> 6;
  const int cl = lane & 15, gq = lane >> 4;
  const int wm = w >> 1, wn = w & 1;
  const int m0 = blockIdx.x << 7, n0 = blockIdx.y << 7;  // tm-fastest dispatch
  const int mat = n0 >> 11;  // 0=Q 1=K 2=V
  f32x4 acc[4][4];
#pragma unroll
  for (int i = 0; i < 4; ++i)
#pragma unroll
    for (int j = 0; j < 4; ++j) {
      f32x4 z = {0.f, 0.f, 0.f, 0.f};
      acc[i][j] = z;
    }
  const int lrow = lane >> 3;
  const int lseg = (lane & 7) ^ lrow;

  for (int k0 = 0; k0 < DD; k0 += 64) {
#pragma unroll
    for (int i = 0; i < 4; ++i) {
      int r0 = ((w << 2) + i) << 3;
      gll16(&A[(size_t)(m0 + r0 + lrow) * DD + k0 + (lseg << 3)], &As[r0 << 6]);
      gll16(&Bt[(size_t)(n0 + r0 + lrow) * DD + k0 + (lseg << 3)], &Bs[r0 << 6]);
    }
    __syncthreads();
#pragma unroll
    for (int ks = 0; ks < 2; ++ks) {
      bf16x8 af[4], bfr[4];
#pragma unroll
      for (int f = 0; f < 4; ++f) {
        int ra = (wm << 6) + (f << 4) + cl;
        af[f] = *reinterpret_cast<const bf16x8*>(
            &As[((ra << 6) + (ks << 5) + (gq << 3)) ^ ((ra & 7) << 3)]);
        int rb = (wn << 6) + (f << 4) + cl;
        bfr[f] = *reinterpret_cast<const bf16x8*>(
            &Bs[((rb << 6) + (ks << 5) + (gq << 3)) ^ ((rb & 7) << 3)]);
      }
#pragma unroll
      for (int fm = 0; fm < 4; ++fm)
#pragma unroll
        for (int fn = 0; fn < 4; ++fn)
          acc[fm][fn] = __builtin_amdgcn_mfma_f32_16x16x32_bf16(
              af[fm], bfr[fn], acc[fm][fn], 0, 0, 0);
    }
    __syncthreads();
  }

  if (mat < 2) {
    // RoPE epilogue (Q/K). pair partner = lane^1 (col c ^ 1)
    const float qs = (mat == 0) ? 0.127517448f : 1.0f;  // log2e/sqrt(128)
    short* Dst = (mat == 0) ? Qb : Kb;
#pragma unroll
    for (int fm = 0; fm < 4; ++fm)
#pragma unroll
      for (int r = 0; r < 4; ++r) {
        int mrow = m0 + (wm << 6) + (fm << 4) + (gq << 2) + r;
        int s = mrow & (SS - 1);
#pragma unroll
        for (int fn = 0; fn < 4; ++fn) {
          int c = (wn << 6) + (fn << 4) + cl;  // head-local col 0..127
          int i = c >> 1;
          float cv = fc[s * 64 + i], sv = fs[s * 64 + i];
          float v = acc[fm][fn][r];
          float vp = __shfl_xor(v, 1, 64);
          float o = (c & 1) ? (v * cv + vp * sv) : (v * cv - vp * sv);
          Dst[(size_t)mrow * DD + ((n0 + c) & (DD - 1))] = f2bf(o * qs);
        }
      }
  } else {
    // V epilogue: transpose via LDS, write Vt (B*H,128,S)
    short* Tt = smem;  // [c][r] stride 136 shorts
#pragma unroll
    for (int fm = 0; fm < 4; ++fm)
#pragma unroll
      for (int fn = 0; fn < 4; ++fn) {
        int c = (wn << 6) + (fn << 4) + cl;
        int rb = (wm << 6) + (fm << 4) + (gq << 2);
        bf16x4 v4;
#pragma unroll
        for (int rr = 0; rr < 4; ++rr) v4[rr] = f2bf(acc[fm][fn][rr]);
        *reinterpret_cast<bf16x4*>(&Tt[c * 136 + rb]) = v4;
      }
    __syncthreads();
    int d = tid >> 1, half = tid & 1;
    int bq = m0 >> 11, s0loc = m0 & (SS - 1);
    int hv = (n0 >> 7) - 32;  // head 0..15
    size_t vb = (((size_t)(bq * 16 + hv) * HDIM + d) * SS) + s0loc + half * 64;
#pragma unroll
    for (int j = 0; j < 8; ++j) {
      bf16x8 v = *reinterpret_cast<const bf16x8*>(&Tt[d * 136 + half * 64 + j * 8]);
      *reinterpret_cast<bf16x8*>(&Vt[vb + j * 8]) = v;
    }
  }
}

// ---------------- Wo GEMM (proven r4 version), fp32 out ----------------
__global__ __launch_bounds__(256) void gemm_kernel(
    const short* __restrict__ A, const short* __restrict__ Bt, float* __restrict__ C,
    int Mdim, int Ndim, int Kdim) {
  __shared__ short As[128 * 64];
  __shared__ short Bs[128 * 64];
  int tid = threadIdx.x;
  int lane = tid & 63, w = tid >> 6;
  int cl = lane & 15, gq = lane >> 4;
  int wm = w >> 1, wn = w & 1;
  int m0 = blockIdx.y << 7, n0 = blockIdx.x << 7;
  f32x4 acc[4][4];
#pragma unroll
  for (int i = 0; i < 4; ++i)
#pragma unroll
    for (int j = 0; j < 4; ++j) {
      f32x4 z = {0.f, 0.f, 0.f, 0.f};
      acc[i][j] = z;
    }
  int lrow = lane >> 3;
  int lseg = (lane & 7) ^ lrow;

  for (int k0 = 0; k0 < Kdim; k0 += 64) {
#pragma unroll
    for (int i = 0; i < 4; ++i) {
      int r0 = ((w << 2) + i) << 3;
      gll16(&A[(size_t)(m0 + r0 + lrow) * Kdim + k0 + (lseg << 3)], &As[r0 << 6]);
      gll16(&Bt[(size_t)(n0 + r0 + lrow) * Kdim + k0 + (lseg << 3)], &Bs[r0 << 6]);
    }
    __syncthreads();
#pragma unroll
    for (int ks = 0; ks < 2; ++ks) {
      bf16x8 af[4], bfr[4];
#pragma unroll
      for (int f = 0; f < 4; ++f) {
        int ra = (wm << 6) + (f << 4) + cl;
        af[f] = *reinterpret_cast<const bf16x8*>(
            &As[((ra << 6) + (ks << 5) + (gq << 3)) ^ ((ra & 7) << 3)]);
        int rb = (wn << 6) + (f << 4) + cl;
        bfr[f] = *reinterpret_cast<const bf16x8*>(
            &Bs[((rb << 6) + (ks << 5) + (gq << 3)) ^ ((rb & 7) << 3)]);
      }
#pragma unroll
      for (int fm = 0; fm < 4; ++fm)
#pragma unroll
        for (int fn = 0; fn < 4; ++fn)
          acc[fm][fn] = __builtin_amdgcn_mfma_f32_16x16x32_bf16(
              af[fm], bfr[fn], acc[fm][fn], 0, 0, 0);
    }
    __syncthreads();
  }
#pragma unroll
  for (int fm = 0; fm < 4; ++fm)
#pragma unroll
    for (int r = 0; r < 4; ++r) {
      int mrow = m0 + (wm << 6) + (fm << 4) + (gq << 2) + r;
#pragma unroll
      for (int fn = 0; fn < 4; ++fn) {
        int ncol = n0 + (wn << 6) + (fn << 4) + cl;
        C[(size_t)mrow * Ndim + ncol] = acc[fm][fn][r];
      }
    }
}

// ---------------- flash attention (proven r4 version) ----------------
// Logits in base-2 units (Q pre-scaled by (1/sqrt(HD))*log2e) -> exp2f.
__global__ __launch_bounds__(256, 2) void attn_kernel(
    const short* __restrict__ Q, const short* __restrict__ K,
    const short* __restrict__ Vt, short* __restrict__ O) {
  __shared__ short Kl[2][64 * 128];
  __shared__ short Vl[2][128 * 64];
  const int id = blockIdx.x;
  const int qi = 15 - (id >> 5);
  const int bh = id & 31;
  const int b = bh >> 4, h = bh & 15;
  const int tid = threadIdx.x;
  const int lane = tid & 63, w = tid >> 6;
  const int l31 = lane & 31, hi = lane >> 5;
  const int qw = qi * 128 + w * 32;
  const int qg = qw + l31;

  const short* Kbase = K + (size_t)b * SS * DD + h * HDIM;
  const short* Vbase = Vt + (size_t)bh * HDIM * SS;
  int krow[4], kq[4], vd[4], vs[4];
#pragma unroll
  for (int i = 0; i < 4; ++i) {
    int c = w * 4 + i;
    krow[i] = c * 4 + (lane >> 4);
    kq[i] = (lane & 15) ^ (krow[i] & 7);
    vd[i] = c * 8 + (lane >> 3);
    vs[i] = (lane & 7) ^ (vd[i] & 7);
  }

  bf16x8 qf[8];
  const size_t qoff = ((size_t)b * SS + qg) * DD + h * HDIM;
#pragma unroll
  for (int s = 0; s < 8; ++s)
    qf[s] = *reinterpret_cast<const bf16x8*>(&Q[qoff + s * 16 + hi * 8]);

  f32x16 ot[4];
#pragma unroll
  for (int dt = 0; dt < 4; ++dt)
#pragma unroll
    for (int r = 0; r < 16; ++r) ot[dt][r] = 0.f;
  float m_run = -INFINITY, l_run = 0.f;

  const int NT = 2 * qi + 2;

#pragma unroll
  for (int i = 0; i < 4; ++i) {
    gll16(Kbase + (size_t)krow[i] * DD + kq[i] * 8, &Kl[0][(w * 4 + i) * 512]);
    gll16(Vbase + (size_t)vd[i] * SS + vs[i] * 8, &Vl[0][(w * 4 + i) * 512]);
  }
  __syncthreads();

  for (int t = 0; t < NT; ++t) {
    const int cur = t & 1;
    if (t + 1 < NT) {
      const int nt64 = (t + 1) * 64;
#pragma unroll
      for (int i = 0; i < 4; ++i) {
        gll16(Kbase + (size_t)(nt64 + krow[i]) * DD + kq[i] * 8,
              &Kl[cur ^ 1][(w * 4 + i) * 512]);
        gll16(Vbase + (size_t)vd[i] * SS + nt64 + vs[i] * 8,
              &Vl[cur ^ 1][(w * 4 + i) * 512]);
      }
    }

    if (t * 64 <= qw + 31) {
      const short* Kc = Kl[cur];
      const short* Vc = Vl[cur];
      f32x16 st0, st1;
#pragma unroll
      for (int r = 0; r < 16; ++r) { st0[r] = 0.f; st1[r] = 0.f; }
      __builtin_amdgcn_s_setprio(1);
#pragma unroll
      for (int s = 0; s < 8; ++s) {
        const int cs = (s * 2 + hi);
        bf16x8 kf0 = *reinterpret_cast<const bf16x8*>(
            &Kc[l31 * 128 + ((cs ^ (l31 & 7)) << 3)]);
        st0 = __builtin_amdgcn_mfma_f32_32x32x16_bf16(kf0, qf[s], st0, 0, 0, 0);
        bf16x8 kf1 = *reinterpret_cast<const bf16x8*>(
            &Kc[(32 + l31) * 128 + ((cs ^ (l31 & 7)) << 3)]);
        st1 = __builtin_amdgcn_mfma_f32_32x32x16_bf16(kf1, qf[s], st1, 0, 0, 0);
      }
      __builtin_amdgcn_s_setprio(0);
      if (t * 64 + 63 > qw) {
#pragma unroll
        for (int r = 0; r < 16; ++r) {
          int dl = (r & 3) + 8 * (r >> 2) + 4 * hi;
          if (t * 64 + dl > qg) st0[r] = -1e30f;
          if (t * 64 + 32 + dl > qg) st1[r] = -1e30f;
        }
      }
      // online softmax (base-2), tree reductions, defer-max
      float mx[16];
#pragma unroll
      for (int r = 0; r < 16; ++r) mx[r] = fmaxf(st0[r], st1[r]);
#pragma unroll
      for (int off = 8; off >= 1; off >>= 1)
#pragma unroll
        for (int r = 0; r < 8; ++r)
          if (r < off) mx[r] = fmaxf(mx[r], mx[r + off]);
      float pm = mx[0];
      {
        auto sw = __builtin_amdgcn_permlane32_swap(asi(pm), asi(pm), false, false);
        pm = fmaxf(asf(sw[0]), asf(sw[1]));
      }
      if (!__all(pm <= m_run + 11.5f)) {
        float mn = fmaxf(m_run, pm);
        float al = exp2f(m_run - mn);
        m_run = mn;
        l_run *= al;
#pragma unroll
        for (int dt = 0; dt < 4; ++dt)
#pragma unroll
          for (int r = 0; r < 16; ++r) ot[dt][r] *= al;
      }
#pragma unroll
      for (int r = 0; r < 16; ++r) st0[r] = exp2f(st0[r] - m_run);
#pragma unroll
      for (int r = 0; r < 16; ++r) st1[r] = exp2f(st1[r] - m_run);
      float sm[16];
#pragma unroll
      for (int r = 0; r < 16; ++r) sm[r] = st0[r] + st1[r];
#pragma unroll
      for (int off = 8; off >= 1; off >>= 1)
#pragma unroll
        for (int r = 0; r < 8; ++r)
          if (r < off) sm[r] += sm[r + off];
      float ps = sm[0];
      {
        auto sw = __builtin_amdgcn_permlane32_swap(asi(ps), asi(ps), false, false);
        ps = asf(sw[0]) + asf(sw[1]);
      }
      l_run += ps;

      // pack P -> bf16 B-frags via cvt_pk + permlane32_swap (T12)
      bf16x8 pf[4];
#pragma unroll
      for (int s = 0; s < 4; ++s) {
        float e0, e1, e2, e3, e4, e5, e6, e7;
        if (s < 2) {
          e0 = st0[8 * s + 0]; e1 = st0[8 * s + 1]; e2 = st0[8 * s + 2]; e3 = st0[8 * s + 3];
          e4 = st0[8 * s + 4]; e5 = st0[8 * s + 5]; e6 = st0[8 * s + 6]; e7 = st0[8 * s + 7];
        } else {
          e0 = st1[8 * (s - 2) + 0]; e1 = st1[8 * (s - 2) + 1]; e2 = st1[8 * (s - 2) + 2]; e3 = st1[8 * (s - 2) + 3];
          e4 = st1[8 * (s - 2) + 4]; e5 = st1[8 * (s - 2) + 5]; e6 = st1[8 * (s - 2) + 6]; e7 = st1[8 * (s - 2) + 7];
        }
        unsigned a0 = cvtpk_bf16(e0, e1);
        unsigned a1 = cvtpk_bf16(e2, e3);
        unsigned b0 = cvtpk_bf16(e4, e5);
        unsigned b1 = cvtpk_bf16(e6, e7);
        auto r0 = __builtin_amdgcn_permlane32_swap((int)a0, (int)b0, false, false);
        auto r1 = __builtin_amdgcn_permlane32_swap((int)a1, (int)b1, false, false);
        union { int u[4]; bf16x8 v; } pk;
        pk.u[0] = r0[0]; pk.u[1] = r1[0]; pk.u[2] = r0[1]; pk.u[3] = r1[1];
        pf[s] = pk.v;
      }

      __builtin_amdgcn_s_setprio(1);
#pragma unroll
      for (int dt = 0; dt < 4; ++dt) {
        const int vr = dt * 32 + l31;
#pragma unroll
        for (int s = 0; s < 4; ++s) {
          bf16x8 vf = *reinterpret_cast<const bf16x8*>(
              &Vc[vr * 64 + (((s * 2 + hi) ^ (vr & 7)) << 3)]);
          ot[dt] = __builtin_amdgcn_mfma_f32_32x32x16_bf16(vf, pf[s], ot[dt], 0, 0, 0);
        }
      }
      __builtin_amdgcn_s_setprio(0);
    }
    __syncthreads();
  }

  float inv = 1.0f / l_run;
  const size_t orow = ((size_t)b * SS + qg) * DD + h * HDIM;
#pragma unroll
  for (int dt = 0; dt < 4; ++dt)
#pragma unroll
    for (int g = 0; g < 4; ++g) {
      bf16x4 v;
#pragma unroll
      for (int k = 0; k < 4; ++k) v[k] = f2bf(ot[dt][4 * g + k] * inv);
      *reinterpret_cast<bf16x4*>(&O[orow + dt * 32 + 8 * g + 4 * hi]) = v;
    }
}

extern "C" void kernel_launch(void* const* d_in, const int* in_sizes, int n_in,
                              void* d_out, int out_size, void* d_ws, size_t ws_size,
                              hipStream_t stream) {
  const float* x = (const float*)d_in[0];
  const float* Wq = (const float*)d_in[1];
  const float* Wk = (const float*)d_in[2];
  const float* Wv = (const float*)d_in[3];
  const float* Wo = (const float*)d_in[4];
  const float* fc = (const float*)d_in[5];
  const float* fs = (const float*)d_in[6];
  float* out = (float*)d_out;
  char* ws = (char*)d_ws;

  short* xb     = (short*)(ws + 0);                      // 16MB; reused as attn_out
  short* WqkvT  = (short*)(ws + (size_t)16 * 1048576);   // 24MB
  short* WoT    = (short*)(ws + (size_t)40 * 1048576);   // 8MB
  short* Qb     = (short*)(ws + (size_t)48 * 1048576);   // 16MB
  short* Kb     = (short*)(ws + (size_t)64 * 1048576);   // 16MB
  short* VtB    = (short*)(ws + (size_t)80 * 1048576);   // 16MB (V transposed)

  cast_bf16_kernel<<<8192, 256, 0, stream>>>(x, xb, 2097152);
  transpose4_kernel<<<dim3(32, 32, 4), 256, 0, stream>>>(Wq, Wk, Wv, Wo, WqkvT, WoT);

  // tm-fastest grid: x = m-tile (32), y = n-tile (48)
  qkv_gemm_kernel<<<dim3(32, 48), 256, 0, stream>>>(xb, WqkvT, Qb, Kb, VtB, fc, fs);

  attn_kernel<<<512, 256, 0, stream>>>(Qb, Kb, VtB, xb);  // attn_out = xb

  gemm_kernel<<<dim3(16, 32), 256, 0, stream>>>(xb, WoT, out, MM, DD, DD);
}

// Round 10
// 274.601 us; speedup vs baseline: 1.1331x; 1.0066x over previous
//
#include <hip/hip_runtime.h>
#include <cstdint>

#define BB 2
#define SS 2048
#define DD 2048
#define HH 16
#define HDIM 128
#define MM (BB * SS)  // 4096

typedef __attribute__((ext_vector_type(8))) short bf16x8;
typedef __attribute__((ext_vector_type(4))) short bf16x4;
typedef __attribute__((ext_vector_type(4))) float f32x4;
typedef __attribute__((ext_vector_type(16))) float f32x16;

__device__ inline short f2bf(float f) {
  union { float f; unsigned u; } v; v.f = f;
  unsigned r = v.u + 0x7FFFu + ((v.u >> 16) & 1u);
  return (short)(r >> 16);
}
__device__ inline float bf2f(short s) {
  union { float f; unsigned u; } v;
  v.u = ((unsigned)(unsigned short)s) << 16;
  return v.f;
}
__device__ inline float asf(int u) { union { int i; float f; } v; v.i = u; return v.f; }
__device__ inline int asi(float f) { union { float f; int i; } v; v.f = f; return v.i; }

__device__ inline unsigned cvtpk_bf16(float lo, float hi) {
  unsigned r;
  asm("v_cvt_pk_bf16_f32 %0, %1, %2" : "=v"(r) : "v"(lo), "v"(hi));
  return r;
}

__device__ inline void gll16(const void* g, void* l) {
  __builtin_amdgcn_global_load_lds(
      (const __attribute__((address_space(1))) void*)g,
      (__attribute__((address_space(3))) void*)l, 16, 0, 0);
}

// ---------------- cast fp32 -> bf16 ----------------
__global__ __launch_bounds__(256) void cast_bf16_kernel(
    const float* __restrict__ x, short* __restrict__ y, int n4) {
  int i = blockIdx.x * 256 + threadIdx.x;
  if (i >= n4) return;
  float4 v = reinterpret_cast<const float4*>(x)[i];
  bf16x4 o;
  o[0] = f2bf(v.x); o[1] = f2bf(v.y); o[2] = f2bf(v.z); o[3] = f2bf(v.w);
  reinterpret_cast<bf16x4*>(y)[i] = o;
}

// ---------------- all 4 weight transposes in ONE launch (z = 0..3) ----------------
__global__ __launch_bounds__(256) void transpose4_kernel(
    const float* __restrict__ Wq, const float* __restrict__ Wk,
    const float* __restrict__ Wv, const float* __restrict__ Wo,
    short* __restrict__ WqkvT, short* __restrict__ WoT) {
  __shared__ short tile[64][65];
  int z = blockIdx.z;
  const float* W = (z == 0) ? Wq : (z == 1) ? Wk : (z == 2) ? Wv : Wo;
  short* Wt = (z < 3) ? (WqkvT + (size_t)z * DD * DD) : WoT;
  int c = threadIdx.x & 63, r4 = threadIdx.x >> 6;
  int n0 = blockIdx.x << 6, k0 = blockIdx.y << 6;
#pragma unroll
  for (int p = 0; p < 16; ++p) {
    int r = (p << 2) + r4;
    tile[c][r] = f2bf(W[(size_t)(k0 + r) * DD + n0 + c]);
  }
  __syncthreads();
#pragma unroll
  for (int p = 0; p < 16; ++p) {
    int r = (p << 2) + r4;
    Wt[(size_t)(n0 + r) * DD + k0 + c] = tile[r][c];
  }
}

// ---------------- fused QKV GEMM: C(4096,6144) = xb * WqkvT^T ----------------
// 128x128 tile, BK=64, 4 waves, 34KB LDS (4 blocks/CU co-resident).
// Epilogues: mat 0/1 RoPE (Q pre-scaled log2e/sqrt(128)); mat 2 V-transpose
// via LDS -> Vt (B*H,128,S).
__global__ __launch_bounds__(256) void qkv_gemm_kernel(
    const short* __restrict__ A, const short* __restrict__ Bt,
    short* __restrict__ Qb, short* __restrict__ Kb, short* __restrict__ Vt,
    const float* __restrict__ fc, const float* __restrict__ fs) {
  __shared__ short smem[128 * 136];  // As(8192)+Bs(8192); epilogue reuses as Tt
  short* As = smem;
  short* Bs = smem + 8192;
  const int tid = threadIdx.x;
  const int lane = tid & 63, w = tid >> 6;
  const int cl = lane & 15, gq = lane >> 4;
  const int wm = w >> 1, wn = w & 1;
  const int m0 = blockIdx.x << 7, n0 = blockIdx.y << 7;  // tm-fastest dispatch
  const int mat = n0 >> 11;  // 0=Q 1=K 2=V
  f32x4 acc[4][4];
#pragma unroll
  for (int i = 0; i < 4; ++i)
#pragma unroll
    for (int j = 0; j < 4; ++j) {
      f32x4 z = {0.f, 0.f, 0.f, 0.f};
      acc[i][j] = z;
    }
  const int lrow = lane >> 3;
  const int lseg = (lane & 7) ^ lrow;

  for (int k0 = 0; k0 < DD; k0 += 64) {
#pragma unroll
    for (int i = 0; i < 4; ++i) {
      int r0 = ((w << 2) + i) << 3;
      gll16(&A[(size_t)(m0 + r0 + lrow) * DD + k0 + (lseg << 3)], &As[r0 << 6]);
      gll16(&Bt[(size_t)(n0 + r0 + lrow) * DD + k0 + (lseg << 3)], &Bs[r0 << 6]);
    }
    __syncthreads();
#pragma unroll
    for (int ks = 0; ks < 2; ++ks) {
      bf16x8 af[4], bfr[4];
#pragma unroll
      for (int f = 0; f < 4; ++f) {
        int ra = (wm << 6) + (f << 4) + cl;
        af[f] = *reinterpret_cast<const bf16x8*>(
            &As[((ra << 6) + (ks << 5) + (gq << 3)) ^ ((ra & 7) << 3)]);
        int rb = (wn << 6) + (f << 4) + cl;
        bfr[f] = *reinterpret_cast<const bf16x8*>(
            &Bs[((rb << 6) + (ks << 5) + (gq << 3)) ^ ((rb & 7) << 3)]);
      }
#pragma unroll
      for (int fm = 0; fm < 4; ++fm)
#pragma unroll
        for (int fn = 0; fn < 4; ++fn)
          acc[fm][fn] = __builtin_amdgcn_mfma_f32_16x16x32_bf16(
              af[fm], bfr[fn], acc[fm][fn], 0, 0, 0);
    }
    __syncthreads();
  }

  if (mat < 2) {
    // RoPE epilogue (Q/K). pair partner = lane^1 (col c ^ 1)
    const float qs = (mat == 0) ? 0.127517448f : 1.0f;  // log2e/sqrt(128)
    short* Dst = (mat == 0) ? Qb : Kb;
#pragma unroll
    for (int fm = 0; fm < 4; ++fm)
#pragma unroll
      for (int r = 0; r < 4; ++r) {
        int mrow = m0 + (wm << 6) + (fm << 4) + (gq << 2) + r;
        int s = mrow & (SS - 1);
#pragma unroll
        for (int fn = 0; fn < 4; ++fn) {
          int c = (wn << 6) + (fn << 4) + cl;  // head-local col 0..127
          int i = c >> 1;
          float cv = fc[s * 64 + i], sv = fs[s * 64 + i];
          float v = acc[fm][fn][r];
          float vp = __shfl_xor(v, 1, 64);
          float o = (c & 1) ? (v * cv + vp * sv) : (v * cv - vp * sv);
          Dst[(size_t)mrow * DD + ((n0 + c) & (DD - 1))] = f2bf(o * qs);
        }
      }
  } else {
    // V epilogue: transpose via LDS, write Vt (B*H,128,S)
    short* Tt = smem;  // [c][r] stride 136 shorts
#pragma unroll
    for (int fm = 0; fm < 4; ++fm)
#pragma unroll
      for (int fn = 0; fn < 4; ++fn) {
        int c = (wn << 6) + (fn << 4) + cl;
        int rb = (wm << 6) + (fm << 4) + (gq << 2);
        bf16x4 v4;
#pragma unroll
        for (int rr = 0; rr < 4; ++rr) v4[rr] = f2bf(acc[fm][fn][rr]);
        *reinterpret_cast<bf16x4*>(&Tt[c * 136 + rb]) = v4;
      }
    __syncthreads();
    int d = tid >> 1, half = tid & 1;
    int bq = m0 >> 11, s0loc = m0 & (SS - 1);
    int hv = (n0 >> 7) - 32;  // head 0..15
    size_t vb = (((size_t)(bq * 16 + hv) * HDIM + d) * SS) + s0loc + half * 64;
#pragma unroll
    for (int j = 0; j < 8; ++j) {
      bf16x8 v = *reinterpret_cast<const bf16x8*>(&Tt[d * 136 + half * 64 + j * 8]);
      *reinterpret_cast<bf16x8*>(&Vt[vb + j * 8]) = v;
    }
  }
}

// ---------------- Wo GEMM (proven r4 version), fp32 out ----------------
__global__ __launch_bounds__(256) void gemm_kernel(
    const short* __restrict__ A, const short* __restrict__ Bt, float* __restrict__ C,
    int Mdim, int Ndim, int Kdim) {
  __shared__ short As[128 * 64];
  __shared__ short Bs[128 * 64];
  int tid = threadIdx.x;
  int lane = tid & 63, w = tid >> 6;
  int cl = lane & 15, gq = lane >> 4;
  int wm = w >> 1, wn = w & 1;
  int m0 = blockIdx.y << 7, n0 = blockIdx.x << 7;
  f32x4 acc[4][4];
#pragma unroll
  for (int i = 0; i < 4; ++i)
#pragma unroll
    for (int j = 0; j < 4; ++j) {
      f32x4 z = {0.f, 0.f, 0.f, 0.f};
      acc[i][j] = z;
    }
  int lrow = lane >> 3;
  int lseg = (lane & 7) ^ lrow;

  for (int k0 = 0; k0 < Kdim; k0 += 64) {
#pragma unroll
    for (int i = 0; i < 4; ++i) {
      int r0 = ((w << 2) + i) << 3;
      gll16(&A[(size_t)(m0 + r0 + lrow) * Kdim + k0 + (lseg << 3)], &As[r0 << 6]);
      gll16(&Bt[(size_t)(n0 + r0 + lrow) * Kdim + k0 + (lseg << 3)], &Bs[r0 << 6]);
    }
    __syncthreads();
#pragma unroll
    for (int ks = 0; ks < 2; ++ks) {
      bf16x8 af[4], bfr[4];
#pragma unroll
      for (int f = 0; f < 4; ++f) {
        int ra = (wm << 6) + (f << 4) + cl;
        af[f] = *reinterpret_cast<const bf16x8*>(
            &As[((ra << 6) + (ks << 5) + (gq << 3)) ^ ((ra & 7) << 3)]);
        int rb = (wn << 6) + (f << 4) + cl;
        bfr[f] = *reinterpret_cast<const bf16x8*>(
            &Bs[((rb << 6) + (ks << 5) + (gq << 3)) ^ ((rb & 7) << 3)]);
      }
#pragma unroll
      for (int fm = 0; fm < 4; ++fm)
#pragma unroll
        for (int fn = 0; fn < 4; ++fn)
          acc[fm][fn] = __builtin_amdgcn_mfma_f32_16x16x32_bf16(
              af[fm], bfr[fn], acc[fm][fn], 0, 0, 0);
    }
    __syncthreads();
  }
#pragma unroll
  for (int fm = 0; fm < 4; ++fm)
#pragma unroll
    for (int r = 0; r < 4; ++r) {
      int mrow = m0 + (wm << 6) + (fm << 4) + (gq << 2) + r;
#pragma unroll
      for (int fn = 0; fn < 4; ++fn) {
        int ncol = n0 + (wn << 6) + (fn << 4) + cl;
        C[(size_t)mrow * Ndim + ncol] = acc[fm][fn][r];
      }
    }
}

// ---------------- flash attention (r4 structure, BALANCED block pairing) ----------------
// 512 blocks = exactly 2/CU; round-robin pairs block id with id+256. Mapping
// qi = (id<256) ? 15-(id>>5) : (id-256)>>5 makes every pair sum NT1+NT2 = 34
// (qi1+qi2 = 15) -> per-CU work constant (was 48..20 under pure LPT).
// Logits in base-2 units (Q pre-scaled by (1/sqrt(HD))*log2e) -> exp2f.
__global__ __launch_bounds__(256, 2) void attn_kernel(
    const short* __restrict__ Q, const short* __restrict__ K,
    const short* __restrict__ Vt, short* __restrict__ O) {
  __shared__ short Kl[2][64 * 128];
  __shared__ short Vl[2][128 * 64];
  const int id = blockIdx.x;
  const int qi = (id < 256) ? (15 - (id >> 5)) : ((id - 256) >> 5);
  const int bh = id & 31;
  const int b = bh >> 4, h = bh & 15;
  const int tid = threadIdx.x;
  const int lane = tid & 63, w = tid >> 6;
  const int l31 = lane & 31, hi = lane >> 5;
  const int qw = qi * 128 + w * 32;
  const int qg = qw + l31;

  const short* Kbase = K + (size_t)b * SS * DD + h * HDIM;
  const short* Vbase = Vt + (size_t)bh * HDIM * SS;
  int krow[4], kq[4], vd[4], vs[4];
#pragma unroll
  for (int i = 0; i < 4; ++i) {
    int c = w * 4 + i;
    krow[i] = c * 4 + (lane >> 4);
    kq[i] = (lane & 15) ^ (krow[i] & 7);
    vd[i] = c * 8 + (lane >> 3);
    vs[i] = (lane & 7) ^ (vd[i] & 7);
  }

  bf16x8 qf[8];
  const size_t qoff = ((size_t)b * SS + qg) * DD + h * HDIM;
#pragma unroll
  for (int s = 0; s < 8; ++s)
    qf[s] = *reinterpret_cast<const bf16x8*>(&Q[qoff + s * 16 + hi * 8]);

  f32x16 ot[4];
#pragma unroll
  for (int dt = 0; dt < 4; ++dt)
#pragma unroll
    for (int r = 0; r < 16; ++r) ot[dt][r] = 0.f;
  float m_run = -INFINITY, l_run = 0.f;

  const int NT = 2 * qi + 2;

#pragma unroll
  for (int i = 0; i < 4; ++i) {
    gll16(Kbase + (size_t)krow[i] * DD + kq[i] * 8, &Kl[0][(w * 4 + i) * 512]);
    gll16(Vbase + (size_t)vd[i] * SS + vs[i] * 8, &Vl[0][(w * 4 + i) * 512]);
  }
  __syncthreads();

  for (int t = 0; t < NT; ++t) {
    const int cur = t & 1;
    if (t + 1 < NT) {
      const int nt64 = (t + 1) * 64;
#pragma unroll
      for (int i = 0; i < 4; ++i) {
        gll16(Kbase + (size_t)(nt64 + krow[i]) * DD + kq[i] * 8,
              &Kl[cur ^ 1][(w * 4 + i) * 512]);
        gll16(Vbase + (size_t)vd[i] * SS + nt64 + vs[i] * 8,
              &Vl[cur ^ 1][(w * 4 + i) * 512]);
      }
    }

    if (t * 64 <= qw + 31) {
      const short* Kc = Kl[cur];
      const short* Vc = Vl[cur];
      f32x16 st0, st1;
#pragma unroll
      for (int r = 0; r < 16; ++r) { st0[r] = 0.f; st1[r] = 0.f; }
      __builtin_amdgcn_s_setprio(1);
#pragma unroll
      for (int s = 0; s < 8; ++s) {
        const int cs = (s * 2 + hi);
        bf16x8 kf0 = *reinterpret_cast<const bf16x8*>(
            &Kc[l31 * 128 + ((cs ^ (l31 & 7)) << 3)]);
        st0 = __builtin_amdgcn_mfma_f32_32x32x16_bf16(kf0, qf[s], st0, 0, 0, 0);
        bf16x8 kf1 = *reinterpret_cast<const bf16x8*>(
            &Kc[(32 + l31) * 128 + ((cs ^ (l31 & 7)) << 3)]);
        st1 = __builtin_amdgcn_mfma_f32_32x32x16_bf16(kf1, qf[s], st1, 0, 0, 0);
      }
      __builtin_amdgcn_s_setprio(0);
      if (t * 64 + 63 > qw) {
#pragma unroll
        for (int r = 0; r < 16; ++r) {
          int dl = (r & 3) + 8 * (r >> 2) + 4 * hi;
          if (t * 64 + dl > qg) st0[r] = -1e30f;
          if (t * 64 + 32 + dl > qg) st1[r] = -1e30f;
        }
      }
      // online softmax (base-2), tree reductions, defer-max
      float mx[16];
#pragma unroll
      for (int r = 0; r < 16; ++r) mx[r] = fmaxf(st0[r], st1[r]);
#pragma unroll
      for (int off = 8; off >= 1; off >>= 1)
#pragma unroll
        for (int r = 0; r < 8; ++r)
          if (r < off) mx[r] = fmaxf(mx[r], mx[r + off]);
      float pm = mx[0];
      {
        auto sw = __builtin_amdgcn_permlane32_swap(asi(pm), asi(pm), false, false);
        pm = fmaxf(asf(sw[0]), asf(sw[1]));
      }
      if (!__all(pm <= m_run + 11.5f)) {
        float mn = fmaxf(m_run, pm);
        float al = exp2f(m_run - mn);
        m_run = mn;
        l_run *= al;
#pragma unroll
        for (int dt = 0; dt < 4; ++dt)
#pragma unroll
          for (int r = 0; r < 16; ++r) ot[dt][r] *= al;
      }
#pragma unroll
      for (int r = 0; r < 16; ++r) st0[r] = exp2f(st0[r] - m_run);
#pragma unroll
      for (int r = 0; r < 16; ++r) st1[r] = exp2f(st1[r] - m_run);
      float sm[16];
#pragma unroll
      for (int r = 0; r < 16; ++r) sm[r] = st0[r] + st1[r];
#pragma unroll
      for (int off = 8; off >= 1; off >>= 1)
#pragma unroll
        for (int r = 0; r < 8; ++r)
          if (r < off) sm[r] += sm[r + off];
      float ps = sm[0];
      {
        auto sw = __builtin_amdgcn_permlane32_swap(asi(ps), asi(ps), false, false);
        ps = asf(sw[0]) + asf(sw[1]);
      }
      l_run += ps;

      // pack P -> bf16 B-frags via cvt_pk + permlane32_swap (T12)
      bf16x8 pf[4];
#pragma unroll
      for (int s = 0; s < 4; ++s) {
        float e0, e1, e2, e3, e4, e5, e6, e7;
        if (s < 2) {
          e0 = st0[8 * s + 0]; e1 = st0[8 * s + 1]; e2 = st0[8 * s + 2]; e3 = st0[8 * s + 3];
          e4 = st0[8 * s + 4]; e5 = st0[8 * s + 5]; e6 = st0[8 * s + 6]; e7 = st0[8 * s + 7];
        } else {
          e0 = st1[8 * (s - 2) + 0]; e1 = st1[8 * (s - 2) + 1]; e2 = st1[8 * (s - 2) + 2]; e3 = st1[8 * (s - 2) + 3];
          e4 = st1[8 * (s - 2) + 4]; e5 = st1[8 * (s - 2) + 5]; e6 = st1[8 * (s - 2) + 6]; e7 = st1[8 * (s - 2) + 7];
        }
        unsigned a0 = cvtpk_bf16(e0, e1);
        unsigned a1 = cvtpk_bf16(e2, e3);
        unsigned b0 = cvtpk_bf16(e4, e5);
        unsigned b1 = cvtpk_bf16(e6, e7);
        auto r0 = __builtin_amdgcn_permlane32_swap((int)a0, (int)b0, false, false);
        auto r1 = __builtin_amdgcn_permlane32_swap((int)a1, (int)b1, false, false);
        union { int u[4]; bf16x8 v; } pk;
        pk.u[0] = r0[0]; pk.u[1] = r1[0]; pk.u[2] = r0[1]; pk.u[3] = r1[1];
        pf[s] = pk.v;
      }

      __builtin_amdgcn_s_setprio(1);
#pragma unroll
      for (int dt = 0; dt < 4; ++dt) {
        const int vr = dt * 32 + l31;
#pragma unroll
        for (int s = 0; s < 4; ++s) {
          bf16x8 vf = *reinterpret_cast<const bf16x8*>(
              &Vc[vr * 64 + (((s * 2 + hi) ^ (vr & 7)) << 3)]);
          ot[dt] = __builtin_amdgcn_mfma_f32_32x32x16_bf16(vf, pf[s], ot[dt], 0, 0, 0);
        }
      }
      __builtin_amdgcn_s_setprio(0);
    }
    __syncthreads();
  }

  float inv = 1.0f / l_run;
  const size_t orow = ((size_t)b * SS + qg) * DD + h * HDIM;
#pragma unroll
  for (int dt = 0; dt < 4; ++dt)
#pragma unroll
    for (int g = 0; g < 4; ++g) {
      bf16x4 v;
#pragma unroll
      for (int k = 0; k < 4; ++k) v[k] = f2bf(ot[dt][4 * g + k] * inv);
      *reinterpret_cast<bf16x4*>(&O[orow + dt * 32 + 8 * g + 4 * hi]) = v;
    }
}

extern "C" void kernel_launch(void* const* d_in, const int* in_sizes, int n_in,
                              void* d_out, int out_size, void* d_ws, size_t ws_size,
                              hipStream_t stream) {
  const float* x = (const float*)d_in[0];
  const float* Wq = (const float*)d_in[1];
  const float* Wk = (const float*)d_in[2];
  const float* Wv = (const float*)d_in[3];
  const float* Wo = (const float*)d_in[4];
  const float* fc = (const float*)d_in[5];
  const float* fs = (const float*)d_in[6];
  float* out = (float*)d_out;
  char* ws = (char*)d_ws;

  short* xb     = (short*)(ws + 0);                      // 16MB; reused as attn_out
  short* WqkvT  = (short*)(ws + (size_t)16 * 1048576);   // 24MB
  short* WoT    = (short*)(ws + (size_t)40 * 1048576);   // 8MB
  short* Qb     = (short*)(ws + (size_t)48 * 1048576);   // 16MB
  short* Kb     = (short*)(ws + (size_t)64 * 1048576);   // 16MB
  short* VtB    = (short*)(ws + (size_t)80 * 1048576);   // 16MB (V transposed)

  cast_bf16_kernel<<<8192, 256, 0, stream>>>(x, xb, 2097152);
  transpose4_kernel<<<dim3(32, 32, 4), 256, 0, stream>>>(Wq, Wk, Wv, Wo, WqkvT, WoT);

  // tm-fastest grid: x = m-tile (32), y = n-tile (48)
  qkv_gemm_kernel<<<dim3(32, 48), 256, 0, stream>>>(xb, WqkvT, Qb, Kb, VtB, fc, fs);

  attn_kernel<<<512, 256, 0, stream>>>(Qb, Kb, VtB, xb);  // attn_out = xb

  gemm_kernel<<<dim3(16, 32), 256, 0, stream>>>(xb, WoT, out, MM, DD, DD);
}